// Round 18
// baseline (79.557 us; speedup 1.0000x reference)
//
#include <hip/hip_runtime.h>
#include <hip/hip_bf16.h>
#include <cstdint>

// GAT fused layer: B=4, N=2048, F=128, H=8, HD=16, all fp32 I/O.
// Identity: exp(leaky(si+sj)) = max(exp(si)exp(sj), exp(.2si)exp(.2sj))
// prep: blocks [0,2048) tpack (transposed u64 mask words), [2048,3072) proj
//   (XW -> wxT bf16 coalesced + EI {ei,ei5} + EjT/Ej5T deinterleaved),
//   block 3072 WoT.  (r15-proven)
// vshuf: wxT -> vfrag MFMA-fragment order (r15-proven).
// gat_part v18: r17 structure (2048 blocks x 256 thr = (b,tile,head-half,
//   j-half), (256,6), V reg-prefetch, barrier-paced, SGPR masks +
//   inverse_ballot) with HAND-PACKED inner math: v_pk_mul_f32 for both
//   branch products of 2 adjacent scores + v_cvt_pk_bf16_f32 packing
//   (VGPR-only asm; r6/r7 failures were "s"-constraint ops only).
//   7 VALU / 2 scores vs ~11 compiler-scalarized.
// combine: r14-proven pair-add + normalize + out-proj + ELU.

typedef float f32x2 __attribute__((ext_vector_type(2)));
typedef float f32x4 __attribute__((ext_vector_type(4)));
typedef __bf16 bf16x8 __attribute__((ext_vector_type(8)));
typedef unsigned long long u64;

__device__ __forceinline__ float lsel(float v, u64 m, u64 lanebit) {
#if __has_builtin(__builtin_amdgcn_inverse_ballot_w64)
    (void)lanebit;
    return __builtin_amdgcn_inverse_ballot_w64(m) ? v : 0.0f;
#else
    return (m & lanebit) ? v : 0.0f;
#endif
}
__device__ __forceinline__ f32x2 pkmul(f32x2 a, f32x2 b) {
    f32x2 d;
    asm("v_pk_mul_f32 %0, %1, %2" : "=v"(d) : "v"(a), "v"(b));
    return d;
}
__device__ __forceinline__ unsigned cvtpk(float lo, float hi) {
    unsigned d;  // dst lo16 = bf16(lo), hi16 = bf16(hi)
    asm("v_cvt_pk_bf16_f32 %0, %1, %2" : "=v"(d) : "v"(lo), "v"(hi));
    return d;
}

__global__ __launch_bounds__(256)
void prep_kernel(const float* __restrict__ x, const float* __restrict__ W,
                 const float* __restrict__ a, const float* __restrict__ Wo,
                 const int* __restrict__ adj,
                 unsigned short* __restrict__ wxT,
                 float2* __restrict__ EI,
                 float* __restrict__ EjT, float* __restrict__ Ej5T,
                 float* __restrict__ WoT,
                 u64* __restrict__ tmask)
{
    const int t = threadIdx.x;

    if (blockIdx.x < 2048) {
        // ---- tpack: adj -> transposed mask words (r11-proven)
        __shared__ int al[16][257];
        const int blk2 = blockIdx.x;
        const int b = blk2 >> 9;
        const int tile = (blk2 >> 2) & 127;
        const int jq = blk2 & 3;
        const int rowbase = b * 2048 + tile * 16;
        const int w = t >> 6, lane = t & 63;
        const int r = lane & 15, jg = lane >> 4;
        const int srow = t >> 4, scol = (t & 15) * 16;

        #pragma unroll
        for (int cc = 0; cc < 2; ++cc) {
            const int jc = jq * 512 + cc * 256;
            const int* gsrc = adj + (size_t)(rowbase + srow) * 2048 + jc + scol;
            #pragma unroll
            for (int q = 0; q < 4; ++q) {
                const int4 v = *reinterpret_cast<const int4*>(&gsrc[q * 4]);
                al[srow][scol + q * 4 + 0] = v.x;
                al[srow][scol + q * 4 + 1] = v.y;
                al[srow][scol + q * 4 + 2] = v.z;
                al[srow][scol + q * 4 + 3] = v.w;
            }
            __syncthreads();
            u64 myw = 0;
            #pragma unroll
            for (int kk = 0; kk < 2; ++kk) {
                const int c0 = w * 64 + kk * 32 + jg * 8;
                const int4 a0 = *reinterpret_cast<const int4*>(&al[r][c0]);
                const int4 a1 = *reinterpret_cast<const int4*>(&al[r][c0 + 4]);
                const int av[8] = {a0.x, a0.y, a0.z, a0.w, a1.x, a1.y, a1.z, a1.w};
                #pragma unroll
                for (int e = 0; e < 8; ++e) {
                    const u64 bal = __ballot(av[e] != 0);
                    const int widx = kk * 8 + e;
                    if (lane == widx) myw = bal;
                }
            }
            __syncthreads();
            const int jtw = jq * 8 + cc * 4 + w;
            if (lane < 16)
                tmask[((size_t)(b * 128 + tile) * 32 + jtw) * 16 + lane] = myw;
        }
        return;
    }

    // ---- proj: blocks [2048,3072), WoT block 3072 (t<128 active)
    const int blk = blockIdx.x - 2048;
    if (blk == 1024) {
        if (t < 128)
            for (int k = 0; k < 128; ++k)
                WoT[k * 128 + t] = Wo[t * 128 + k];
        return;
    }
    __shared__ float xl[8 * 128];
    __shared__ float xw[8 * 128];
    const int row0 = blk * 8;
    if (t < 128) {
        #pragma unroll
        for (int r = 0; r < 8; ++r)
            xl[r * 128 + t] = x[(size_t)(row0 + r) * 128 + t];
    }
    __syncthreads();

    if (t < 128) {
        float acc[8] = {0.f, 0.f, 0.f, 0.f, 0.f, 0.f, 0.f, 0.f};
        for (int k = 0; k < 128; k += 4) {
            const float w0 = W[(k + 0) * 128 + t];
            const float w1 = W[(k + 1) * 128 + t];
            const float w2 = W[(k + 2) * 128 + t];
            const float w3 = W[(k + 3) * 128 + t];
            #pragma unroll
            for (int r = 0; r < 8; ++r) {
                const float4 xv = *reinterpret_cast<const float4*>(&xl[r * 128 + k]);
                acc[r] += xv.x * w0 + xv.y * w1 + xv.z * w2 + xv.w * w3;
            }
        }
        #pragma unroll
        for (int r = 0; r < 8; ++r) xw[r * 128 + t] = acc[r];
    }
    __syncthreads();

    if (t < 128) {
        const int b = row0 >> 11, n0 = row0 & 2047;
        bf16x8 st;
        #pragma unroll
        for (int r = 0; r < 8; ++r) st[r] = (__bf16)xw[r * 128 + t];
        *reinterpret_cast<bf16x8*>(&wxT[((size_t)(b * 128 + t)) * 2048 + n0]) = st;

        const int r = t >> 4, h = (t >> 1) & 7, s = t & 1;
        float dot = 0.f;
        #pragma unroll
        for (int d = 0; d < 16; ++d)
            dot += xw[r * 128 + h * 16 + d] * a[h * 32 + s * 16 + d];
        const float ef  = __expf(dot);
        const float ef5 = __expf(0.2f * dot);
        const int idx = (b * 8 + h) * 2048 + n0 + r;
        if (s) { EjT[idx] = ef; Ej5T[idx] = ef5; }
        else   { float2 ev; ev.x = ef; ev.y = ef5; EI[idx] = ev; }
    }
}

// wxT [b*128+f][2048 n] -> vfrag [((b*8+h)*64 + w32)*64 + lane] (r15-proven)
__global__ __launch_bounds__(256)
void vshuf_kernel(const unsigned short* __restrict__ wxT,
                  unsigned short* __restrict__ vfrag)
{
    const int gid = blockIdx.x * 256 + threadIdx.x;   // 0..131071
    const int lane = gid & 63;
    const int w32 = (gid >> 6) & 63;
    const int bh = gid >> 12;                          // b*8 + h
    const int b = bh >> 3, h = bh & 7;
    const int f = h * 16 + (lane & 15);
    const int j = w32 * 32 + (lane >> 4) * 8;
    const bf16x8 v = *reinterpret_cast<const bf16x8*>(
        &wxT[((size_t)(b * 128 + f)) * 2048 + j]);
    *reinterpret_cast<bf16x8*>(&vfrag[(size_t)gid * 8]) = v;
}

__global__ __launch_bounds__(256, 6)
void gat_part(const u64* __restrict__ tmask,
              const unsigned short* __restrict__ vfrag,
              const float2* __restrict__ EI,
              const float* __restrict__ EjT, const float* __restrict__ Ej5T,
              float* __restrict__ pacc, float* __restrict__ psum)
{
    const int tid = threadIdx.x;
    const int hw = tid >> 6;             // local head 0..3
    const int lane = tid & 63;
    const int r = lane & 15;             // A-frag row / B-frag col (feature)
    const int jg = lane >> 4;
    const u64 lanebit = 1ull << lane;
    // all 4 subs of one (b,tile) share an XCD (r14-proven mapping)
    const int x = blockIdx.x & 7, w = blockIdx.x >> 3;
    const int tg = x * 64 + (w & 63);    // 0..511 = b*128+tile
    const int sub = w >> 6;              // 0..3
    const int jh = sub >> 1, hg = sub & 1;
    const int b = tg >> 7;
    const int tile = tg & 127;
    const int ibase = tile << 4;
    const int h = hg * 4 + hw;

    __shared__ __align__(16) float EjL[2][4][128];    // 4 KB
    __shared__ __align__(16) float Ej5L[2][4][128];   // 4 KB

    const int eb = (b * 8 + h) * 2048;
    const float2 q0 = EI[eb + ibase + r];
    f32x2 EiE, Ei5E;
    EiE[0] = q0.x;  EiE[1] = q0.x;       // {exp(ei), exp(ei)}
    Ei5E[0] = q0.y; Ei5E[1] = q0.y;      // {exp(.2ei), exp(.2ei)}
    const u64* tmrow = tmask + (size_t)(b * 128 + tile) * 512;
    const unsigned short* vfr = vfrag + (size_t)(b * 8 + h) * 64 * 64 * 8;
    const float* EjG  = EjT  + eb;
    const float* Ej5G = Ej5T + eb;

    f32x4 acc  = {0.f, 0.f, 0.f, 0.f};
    f32x4 accS = {0.f, 0.f, 0.f, 0.f};
    bf16x8 ones;
    #pragma unroll
    for (int e2 = 0; e2 < 8; ++e2) ones[e2] = (__bf16)1.0f;

    const int jbase = jh * 1024;
    const int wbase = jh * 32;

    bf16x8 vC0, vC1, vC2, vC3, vN0, vN1, vN2, vN3;
    // ---- prologue: V chunk 0 -> regs, Ej chunk 0 -> LDS buf 0
    vC0 = *reinterpret_cast<const bf16x8*>(&vfr[((wbase + 0) * 64 + lane) * 8]);
    vC1 = *reinterpret_cast<const bf16x8*>(&vfr[((wbase + 1) * 64 + lane) * 8]);
    vC2 = *reinterpret_cast<const bf16x8*>(&vfr[((wbase + 2) * 64 + lane) * 8]);
    vC3 = *reinterpret_cast<const bf16x8*>(&vfr[((wbase + 3) * 64 + lane) * 8]);
    {
        const float2 s0 = *reinterpret_cast<const float2*>(&EjG[jbase + lane * 2]);
        const float2 s1 = *reinterpret_cast<const float2*>(&Ej5G[jbase + lane * 2]);
        *reinterpret_cast<float2*>(&EjL[0][hw][lane * 2]) = s0;
        *reinterpret_cast<float2*>(&Ej5L[0][hw][lane * 2]) = s1;
    }
    __syncthreads();

    int cur = 0;
    for (int c = 0; c < 8; ++c) {
        // ---- issue next chunk's loads (c=7 wraps within half: in-bounds,
        //      staged/rotated but never computed)
        const int cn = (c + 1) & 7;
        const int w32n = wbase + cn * 4;
        const int jn = jbase + cn * 128;
        vN0 = *reinterpret_cast<const bf16x8*>(&vfr[((w32n + 0) * 64 + lane) * 8]);
        vN1 = *reinterpret_cast<const bf16x8*>(&vfr[((w32n + 1) * 64 + lane) * 8]);
        vN2 = *reinterpret_cast<const bf16x8*>(&vfr[((w32n + 2) * 64 + lane) * 8]);
        vN3 = *reinterpret_cast<const bf16x8*>(&vfr[((w32n + 3) * 64 + lane) * 8]);
        const float2 sn  = *reinterpret_cast<const float2*>(&EjG[jn + lane * 2]);
        const float2 sn5 = *reinterpret_cast<const float2*>(&Ej5G[jn + lane * 2]);
        __builtin_amdgcn_sched_barrier(0);

        // ---- masks for current chunk (block-uniform -> scalar loads)
        const u64* tmw = tmrow + (jh * 16 + c * 2) * 16;
        u64 mwA[16], mwB[16];
        #pragma unroll
        for (int e2 = 0; e2 < 16; ++e2) mwA[e2] = tmw[e2];
        #pragma unroll
        for (int e2 = 0; e2 < 16; ++e2) mwB[e2] = tmw[16 + e2];

        // ---- compute current chunk: 4 kk, hand-packed math
        #pragma unroll
        for (int kk = 0; kk < 4; ++kk) {
            const int jloc = kk * 32 + jg * 8;
            const float4 e0 = *reinterpret_cast<const float4*>(&EjL[cur][hw][jloc]);
            const float4 e1 = *reinterpret_cast<const float4*>(&EjL[cur][hw][jloc + 4]);
            const float4 f0 = *reinterpret_cast<const float4*>(&Ej5L[cur][hw][jloc]);
            const float4 f1 = *reinterpret_cast<const float4*>(&Ej5L[cur][hw][jloc + 4]);
            const bf16x8 v = (kk == 0) ? vC0 : (kk == 1) ? vC1 : (kk == 2) ? vC2 : vC3;
            const u64* mwp = (kk < 2) ? mwA : mwB;
            const int mof = (kk & 1) * 8;
            const float ee[8] = {e0.x, e0.y, e0.z, e0.w, e1.x, e1.y, e1.z, e1.w};
            const float ff[8] = {f0.x, f0.y, f0.z, f0.w, f1.x, f1.y, f1.z, f1.w};
            unsigned au[4];
            #pragma unroll
            for (int q = 0; q < 4; ++q) {
                f32x2 ejp;  ejp[0]  = ee[2 * q]; ejp[1]  = ee[2 * q + 1];
                f32x2 ej5p; ej5p[0] = ff[2 * q]; ej5p[1] = ff[2 * q + 1];
                const f32x2 t1 = pkmul(ejp, EiE);     // {Ei*Ej0, Ei*Ej1}
                const f32x2 t2 = pkmul(ej5p, Ei5E);   // {Ei5*Ej50, Ei5*Ej51}
                const float m0 = fmaxf(t1[0], t2[0]);
                const float m1 = fmaxf(t1[1], t2[1]);
                const float p0 = lsel(m0, mwp[mof + 2 * q],     lanebit);
                const float p1 = lsel(m1, mwp[mof + 2 * q + 1], lanebit);
                au[q] = cvtpk(p0, p1);                // 2 bf16 in one u32
            }
            union { unsigned u[4]; bf16x8 v8; } cvt;
            cvt.u[0] = au[0]; cvt.u[1] = au[1]; cvt.u[2] = au[2]; cvt.u[3] = au[3];
            acc  = __builtin_amdgcn_mfma_f32_16x16x32_bf16(cvt.v8, v,    acc,  0, 0, 0);
            accS = __builtin_amdgcn_mfma_f32_16x16x32_bf16(cvt.v8, ones, accS, 0, 0, 0);
        }

        // ---- stage next Ej; barrier drains vmcnt (V loads complete)
        const int nb = cur ^ 1;
        *reinterpret_cast<float2*>(&EjL[nb][hw][lane * 2]) = sn;
        *reinterpret_cast<float2*>(&Ej5L[nb][hw][lane * 2]) = sn5;
        __syncthreads();
        vC0 = vN0; vC1 = vN1; vC2 = vN2; vC3 = vN3;
        cur = nb;
    }

    // ---- partials (r14 layout). C/D: col = r (feature), row = jg*4+q.
    const size_t pb = (size_t)((b * 128 + tile) * 2 + jh);
    float* pa = pacc + pb * 2048;
    float* ps = psum + pb * 128;
    #pragma unroll
    for (int q = 0; q < 4; ++q) {
        const int row = jg * 4 + q;
        pa[row * 128 + hg * 64 + hw * 16 + r] = acc[q];
        if (r == 0) ps[(hg * 4 + hw) * 16 + row] = accS[q];
    }
}

__global__ __launch_bounds__(256)
void combine_kernel(const float* __restrict__ pacc, const float* __restrict__ psum,
                    const float* __restrict__ WoT, const float* __restrict__ bo,
                    float* __restrict__ out)
{
    const int tid = threadIdx.x;
    const int bid = (blockIdx.x & 7) * 64 + (blockIdx.x >> 3);
    const int b = bid >> 7;
    const int tile = bid & 127;
    const int ibase = tile << 4;

    __shared__ float hl[16][128];
    const size_t pb0 = (size_t)((b * 128 + tile) * 2);
    const float* pa0 = pacc + pb0 * 2048;
    const float* pa1 = pa0 + 2048;
    const float* ps0 = psum + pb0 * 128;
    const float* ps1 = ps0 + 128;

    #pragma unroll
    for (int k = 0; k < 8; ++k) {
        const int idx = k * 256 + tid;        // 0..2047
        const int row = idx >> 7, f = idx & 127, h = f >> 4;
        const float num = pa0[idx] + pa1[idx];
        const float den = ps0[h * 16 + row] + ps1[h * 16 + row];
        const float inv = (den > 0.f) ? 1.f / den : 0.f;   // empty row -> 0
        hl[row][f] = num * inv;
    }
    __syncthreads();

    const int f = tid & 127;
    const int rg = tid >> 7;
    float o[8] = {0.f, 0.f, 0.f, 0.f, 0.f, 0.f, 0.f, 0.f};
    for (int k = 0; k < 128; k += 4) {
        const float w0 = WoT[(k + 0) * 128 + f];
        const float w1 = WoT[(k + 1) * 128 + f];
        const float w2 = WoT[(k + 2) * 128 + f];
        const float w3 = WoT[(k + 3) * 128 + f];
        #pragma unroll
        for (int q = 0; q < 8; ++q) {
            const float4 hv = *reinterpret_cast<const float4*>(&hl[rg * 8 + q][k]);
            o[q] += hv.x * w0 + hv.y * w1 + hv.z * w2 + hv.w * w3;
        }
    }
    const float bv = bo[f];
    #pragma unroll
    for (int q = 0; q < 8; ++q) {
        float v = o[q] + bv;
        v = (v > 0.f) ? v : (__expf(v) - 1.f);
        out[(size_t)(b * 2048 + ibase + rg * 8 + q) * 128 + f] = v;
    }
}

extern "C" void kernel_launch(void* const* d_in, const int* in_sizes, int n_in,
                              void* d_out, int out_size, void* d_ws, size_t ws_size,
                              hipStream_t stream) {
    const float* x   = (const float*)d_in[0];
    const int*   adj = (const int*)d_in[1];
    const float* W   = (const float*)d_in[2];
    const float* a   = (const float*)d_in[3];
    const float* Wo  = (const float*)d_in[4];
    const float* bo  = (const float*)d_in[5];
    float* out = (float*)d_out;

    // ws: wxT 2MB | EI 512K | EjT 256K | Ej5T 256K | WoT 64K | tmask 2MB |
    //     vfrag 2MB | pacc 8MB | psum 512K   (~15.6 MB)
    char* ws = (char*)d_ws;
    unsigned short* wxT = (unsigned short*)ws;
    float2* EI  = (float2*)(ws + (size_t)2 * 1024 * 1024);
    float* EjT  = (float*)(EI + 4 * 8 * 2048);
    float* Ej5T = EjT + 4 * 8 * 2048;
    float* WoT  = Ej5T + 4 * 8 * 2048;
    u64* tmask = (u64*)(WoT + 128 * 128);
    unsigned short* vfrag = (unsigned short*)(tmask + (size_t)512 * 512);
    float* pacc = (float*)(vfrag + (size_t)1024 * 1024);
    float* psum = pacc + (size_t)1024 * 2048;

    prep_kernel<<<dim3(2048 + 1025), dim3(256), 0, stream>>>(
        x, W, a, Wo, adj, wxT, EI, EjT, Ej5T, WoT, tmask);
    vshuf_kernel<<<dim3(512), dim3(256), 0, stream>>>(wxT, vfrag);
    gat_part<<<dim3(2048), dim3(256), 0, stream>>>(
        tmask, vfrag, EI, EjT, Ej5T, pacc, psum);
    combine_kernel<<<dim3(512), dim3(256), 0, stream>>>(
        pacc, psum, WoT, bo, out);
}

// Round 19
// 72.312 us; speedup vs baseline: 1.1002x; 1.1002x over previous
//
#include <hip/hip_runtime.h>
#include <hip/hip_bf16.h>
#include <cstdint>

// GAT fused layer: B=4, N=2048, F=128, H=8, HD=16, all fp32 I/O.
// Identity: exp(leaky(si+sj)) = max(exp(si)exp(sj), exp(.2si)exp(.2sj))
// prep: blocks [0,2048) tpack (transposed u64 mask words), [2048,3072) proj
//   (XW -> vfrag DIRECT in MFMA-fragment order (r17-proven) + EI {ei,ei5} +
//   EjT/Ej5T deinterleaved), block 3072 WoT.
// gat_part v19 = r18 body + ONE change: ALL 16 ds_read_b128 of the chunk's
//   Ej/Ej5 hoisted to chunk top into statically-indexed register arrays
//   (compiler keeps per-kk loads just-in-time otherwise -> ~150cyc lgkm
//   wait x32/wave was the 53% stall). launch_bounds(256,4) for VGPR room.
// combine: r14-proven pair-add + normalize + out-proj + ELU.

typedef float f32x2 __attribute__((ext_vector_type(2)));
typedef float f32x4 __attribute__((ext_vector_type(4)));
typedef __bf16 bf16x8 __attribute__((ext_vector_type(8)));
typedef unsigned long long u64;

__device__ __forceinline__ float lsel(float v, u64 m, u64 lanebit) {
#if __has_builtin(__builtin_amdgcn_inverse_ballot_w64)
    (void)lanebit;
    return __builtin_amdgcn_inverse_ballot_w64(m) ? v : 0.0f;
#else
    return (m & lanebit) ? v : 0.0f;
#endif
}
__device__ __forceinline__ f32x2 pkmul(f32x2 a, f32x2 b) {
    f32x2 d;
    asm("v_pk_mul_f32 %0, %1, %2" : "=v"(d) : "v"(a), "v"(b));
    return d;
}
__device__ __forceinline__ unsigned cvtpk(float lo, float hi) {
    unsigned d;  // dst lo16 = bf16(lo), hi16 = bf16(hi)
    asm("v_cvt_pk_bf16_f32 %0, %1, %2" : "=v"(d) : "v"(lo), "v"(hi));
    return d;
}

__global__ __launch_bounds__(256)
void prep_kernel(const float* __restrict__ x, const float* __restrict__ W,
                 const float* __restrict__ a, const float* __restrict__ Wo,
                 const int* __restrict__ adj,
                 unsigned short* __restrict__ vfrag,
                 float2* __restrict__ EI,
                 float* __restrict__ EjT, float* __restrict__ Ej5T,
                 float* __restrict__ WoT,
                 u64* __restrict__ tmask)
{
    const int t = threadIdx.x;

    if (blockIdx.x < 2048) {
        // ---- tpack: adj -> transposed mask words (r11-proven)
        __shared__ int al[16][257];
        const int blk2 = blockIdx.x;
        const int b = blk2 >> 9;
        const int tile = (blk2 >> 2) & 127;
        const int jq = blk2 & 3;
        const int rowbase = b * 2048 + tile * 16;
        const int w = t >> 6, lane = t & 63;
        const int r = lane & 15, jg = lane >> 4;
        const int srow = t >> 4, scol = (t & 15) * 16;

        #pragma unroll
        for (int cc = 0; cc < 2; ++cc) {
            const int jc = jq * 512 + cc * 256;
            const int* gsrc = adj + (size_t)(rowbase + srow) * 2048 + jc + scol;
            #pragma unroll
            for (int q = 0; q < 4; ++q) {
                const int4 v = *reinterpret_cast<const int4*>(&gsrc[q * 4]);
                al[srow][scol + q * 4 + 0] = v.x;
                al[srow][scol + q * 4 + 1] = v.y;
                al[srow][scol + q * 4 + 2] = v.z;
                al[srow][scol + q * 4 + 3] = v.w;
            }
            __syncthreads();
            u64 myw = 0;
            #pragma unroll
            for (int kk = 0; kk < 2; ++kk) {
                const int c0 = w * 64 + kk * 32 + jg * 8;
                const int4 a0 = *reinterpret_cast<const int4*>(&al[r][c0]);
                const int4 a1 = *reinterpret_cast<const int4*>(&al[r][c0 + 4]);
                const int av[8] = {a0.x, a0.y, a0.z, a0.w, a1.x, a1.y, a1.z, a1.w};
                #pragma unroll
                for (int e = 0; e < 8; ++e) {
                    const u64 bal = __ballot(av[e] != 0);
                    const int widx = kk * 8 + e;
                    if (lane == widx) myw = bal;
                }
            }
            __syncthreads();
            const int jtw = jq * 8 + cc * 4 + w;
            if (lane < 16)
                tmask[((size_t)(b * 128 + tile) * 32 + jtw) * 16 + lane] = myw;
        }
        return;
    }

    // ---- proj: blocks [2048,3072), WoT block 3072 (t<128 active)
    const int blk = blockIdx.x - 2048;
    if (blk == 1024) {
        if (t < 128)
            for (int k = 0; k < 128; ++k)
                WoT[k * 128 + t] = Wo[t * 128 + k];
        return;
    }
    __shared__ float xl[8 * 128];
    __shared__ float xw[8 * 128];
    const int row0 = blk * 8;
    if (t < 128) {
        #pragma unroll
        for (int r = 0; r < 8; ++r)
            xl[r * 128 + t] = x[(size_t)(row0 + r) * 128 + t];
    }
    __syncthreads();

    if (t < 128) {
        float acc[8] = {0.f, 0.f, 0.f, 0.f, 0.f, 0.f, 0.f, 0.f};
        for (int k = 0; k < 128; k += 4) {
            const float w0 = W[(k + 0) * 128 + t];
            const float w1 = W[(k + 1) * 128 + t];
            const float w2 = W[(k + 2) * 128 + t];
            const float w3 = W[(k + 3) * 128 + t];
            #pragma unroll
            for (int r = 0; r < 8; ++r) {
                const float4 xv = *reinterpret_cast<const float4*>(&xl[r * 128 + k]);
                acc[r] += xv.x * w0 + xv.y * w1 + xv.z * w2 + xv.w * w3;
            }
        }
        #pragma unroll
        for (int r = 0; r < 8; ++r) xw[r * 128 + t] = acc[r];
    }
    __syncthreads();

    if (t < 128) {
        const int b = row0 >> 11, n0 = row0 & 2047;
        // vfrag DIRECT (r17-proven): thread t=f owns 8 consecutive n.
        bf16x8 st;
        #pragma unroll
        for (int r = 0; r < 8; ++r) st[r] = (__bf16)xw[r * 128 + t];
        const int hh = t >> 4, rr = t & 15;
        const int w32 = n0 >> 5, jgp = (n0 >> 3) & 3;
        *reinterpret_cast<bf16x8*>(
            &vfrag[(((size_t)(b * 8 + hh) * 64 + w32) * 64 + jgp * 16 + rr) * 8]) = st;

        const int r = t >> 4, h = (t >> 1) & 7, s = t & 1;
        float dot = 0.f;
        #pragma unroll
        for (int d = 0; d < 16; ++d)
            dot += xw[r * 128 + h * 16 + d] * a[h * 32 + s * 16 + d];
        const float ef  = __expf(dot);
        const float ef5 = __expf(0.2f * dot);
        const int idx = (b * 8 + h) * 2048 + n0 + r;
        if (s) { EjT[idx] = ef; Ej5T[idx] = ef5; }
        else   { float2 ev; ev.x = ef; ev.y = ef5; EI[idx] = ev; }
    }
}

__global__ __launch_bounds__(256, 4)
void gat_part(const u64* __restrict__ tmask,
              const unsigned short* __restrict__ vfrag,
              const float2* __restrict__ EI,
              const float* __restrict__ EjT, const float* __restrict__ Ej5T,
              float* __restrict__ pacc, float* __restrict__ psum)
{
    const int tid = threadIdx.x;
    const int hw = tid >> 6;             // local head 0..3
    const int lane = tid & 63;
    const int r = lane & 15;             // A-frag row / B-frag col (feature)
    const int jg = lane >> 4;
    const u64 lanebit = 1ull << lane;
    // all 4 subs of one (b,tile) share an XCD (r14-proven mapping)
    const int x = blockIdx.x & 7, w = blockIdx.x >> 3;
    const int tg = x * 64 + (w & 63);    // 0..511 = b*128+tile
    const int sub = w >> 6;              // 0..3
    const int jh = sub >> 1, hg = sub & 1;
    const int b = tg >> 7;
    const int tile = tg & 127;
    const int ibase = tile << 4;
    const int h = hg * 4 + hw;

    __shared__ __align__(16) float EjL[2][4][128];    // 4 KB
    __shared__ __align__(16) float Ej5L[2][4][128];   // 4 KB

    const int eb = (b * 8 + h) * 2048;
    const float2 q0 = EI[eb + ibase + r];
    f32x2 EiE, Ei5E;
    EiE[0] = q0.x;  EiE[1] = q0.x;       // {exp(ei), exp(ei)}
    Ei5E[0] = q0.y; Ei5E[1] = q0.y;      // {exp(.2ei), exp(.2ei)}
    const u64* tmrow = tmask + (size_t)(b * 128 + tile) * 512;
    const unsigned short* vfr = vfrag + (size_t)(b * 8 + h) * 64 * 64 * 8;
    const float* EjG  = EjT  + eb;
    const float* Ej5G = Ej5T + eb;

    f32x4 acc  = {0.f, 0.f, 0.f, 0.f};
    f32x4 accS = {0.f, 0.f, 0.f, 0.f};
    bf16x8 ones;
    #pragma unroll
    for (int e2 = 0; e2 < 8; ++e2) ones[e2] = (__bf16)1.0f;

    const int jbase = jh * 1024;
    const int wbase = jh * 32;

    bf16x8 vC0, vC1, vC2, vC3, vN0, vN1, vN2, vN3;
    // ---- prologue: V chunk 0 -> regs, Ej chunk 0 -> LDS buf 0
    vC0 = *reinterpret_cast<const bf16x8*>(&vfr[((wbase + 0) * 64 + lane) * 8]);
    vC1 = *reinterpret_cast<const bf16x8*>(&vfr[((wbase + 1) * 64 + lane) * 8]);
    vC2 = *reinterpret_cast<const bf16x8*>(&vfr[((wbase + 2) * 64 + lane) * 8]);
    vC3 = *reinterpret_cast<const bf16x8*>(&vfr[((wbase + 3) * 64 + lane) * 8]);
    {
        const float2 s0 = *reinterpret_cast<const float2*>(&EjG[jbase + lane * 2]);
        const float2 s1 = *reinterpret_cast<const float2*>(&Ej5G[jbase + lane * 2]);
        *reinterpret_cast<float2*>(&EjL[0][hw][lane * 2]) = s0;
        *reinterpret_cast<float2*>(&Ej5L[0][hw][lane * 2]) = s1;
    }
    __syncthreads();

    int cur = 0;
    for (int c = 0; c < 8; ++c) {
        // ---- issue next chunk's loads (c=7 wraps within half: in-bounds,
        //      staged/rotated but never computed)
        const int cn = (c + 1) & 7;
        const int w32n = wbase + cn * 4;
        const int jn = jbase + cn * 128;
        vN0 = *reinterpret_cast<const bf16x8*>(&vfr[((w32n + 0) * 64 + lane) * 8]);
        vN1 = *reinterpret_cast<const bf16x8*>(&vfr[((w32n + 1) * 64 + lane) * 8]);
        vN2 = *reinterpret_cast<const bf16x8*>(&vfr[((w32n + 2) * 64 + lane) * 8]);
        vN3 = *reinterpret_cast<const bf16x8*>(&vfr[((w32n + 3) * 64 + lane) * 8]);
        const float2 sn  = *reinterpret_cast<const float2*>(&EjG[jn + lane * 2]);
        const float2 sn5 = *reinterpret_cast<const float2*>(&Ej5G[jn + lane * 2]);
        __builtin_amdgcn_sched_barrier(0);

        // ---- masks for current chunk (block-uniform -> scalar loads)
        const u64* tmw = tmrow + (jh * 16 + c * 2) * 16;
        u64 mwA[16], mwB[16];
        #pragma unroll
        for (int e2 = 0; e2 < 16; ++e2) mwA[e2] = tmw[e2];
        #pragma unroll
        for (int e2 = 0; e2 < 16; ++e2) mwB[e2] = tmw[16 + e2];

        // ---- v19: hoist ALL of this chunk's LDS reads to the top
        //      (16x ds_read_b128 into static register arrays; kks 1-3 find
        //      their data resident instead of paying ~150cyc each)
        float4 E0[4], E1[4], F0[4], F1[4];
        #pragma unroll
        for (int kk = 0; kk < 4; ++kk) {
            const int jloc = kk * 32 + jg * 8;
            E0[kk] = *reinterpret_cast<const float4*>(&EjL[cur][hw][jloc]);
            E1[kk] = *reinterpret_cast<const float4*>(&EjL[cur][hw][jloc + 4]);
            F0[kk] = *reinterpret_cast<const float4*>(&Ej5L[cur][hw][jloc]);
            F1[kk] = *reinterpret_cast<const float4*>(&Ej5L[cur][hw][jloc + 4]);
        }

        // ---- compute current chunk: 4 kk, hand-packed math (r18-proven)
        #pragma unroll
        for (int kk = 0; kk < 4; ++kk) {
            const bf16x8 v = (kk == 0) ? vC0 : (kk == 1) ? vC1 : (kk == 2) ? vC2 : vC3;
            const u64* mwp = (kk < 2) ? mwA : mwB;
            const int mof = (kk & 1) * 8;
            const float4 e0 = E0[kk], e1 = E1[kk], f0 = F0[kk], f1 = F1[kk];
            const float ee[8] = {e0.x, e0.y, e0.z, e0.w, e1.x, e1.y, e1.z, e1.w};
            const float ff[8] = {f0.x, f0.y, f0.z, f0.w, f1.x, f1.y, f1.z, f1.w};
            unsigned au[4];
            #pragma unroll
            for (int q = 0; q < 4; ++q) {
                f32x2 ejp;  ejp[0]  = ee[2 * q]; ejp[1]  = ee[2 * q + 1];
                f32x2 ej5p; ej5p[0] = ff[2 * q]; ej5p[1] = ff[2 * q + 1];
                const f32x2 t1 = pkmul(ejp, EiE);     // {Ei*Ej0, Ei*Ej1}
                const f32x2 t2 = pkmul(ej5p, Ei5E);   // {Ei5*Ej50, Ei5*Ej51}
                const float m0 = fmaxf(t1[0], t2[0]);
                const float m1 = fmaxf(t1[1], t2[1]);
                const float p0 = lsel(m0, mwp[mof + 2 * q],     lanebit);
                const float p1 = lsel(m1, mwp[mof + 2 * q + 1], lanebit);
                au[q] = cvtpk(p0, p1);                // 2 bf16 in one u32
            }
            union { unsigned u[4]; bf16x8 v8; } cvt;
            cvt.u[0] = au[0]; cvt.u[1] = au[1]; cvt.u[2] = au[2]; cvt.u[3] = au[3];
            acc  = __builtin_amdgcn_mfma_f32_16x16x32_bf16(cvt.v8, v,    acc,  0, 0, 0);
            accS = __builtin_amdgcn_mfma_f32_16x16x32_bf16(cvt.v8, ones, accS, 0, 0, 0);
        }

        // ---- stage next Ej; barrier drains vmcnt (V loads complete)
        const int nb = cur ^ 1;
        *reinterpret_cast<float2*>(&EjL[nb][hw][lane * 2]) = sn;
        *reinterpret_cast<float2*>(&Ej5L[nb][hw][lane * 2]) = sn5;
        __syncthreads();
        vC0 = vN0; vC1 = vN1; vC2 = vN2; vC3 = vN3;
        cur = nb;
    }

    // ---- partials (r14 layout). C/D: col = r (feature), row = jg*4+q.
    const size_t pb = (size_t)((b * 128 + tile) * 2 + jh);
    float* pa = pacc + pb * 2048;
    float* ps = psum + pb * 128;
    #pragma unroll
    for (int q = 0; q < 4; ++q) {
        const int row = jg * 4 + q;
        pa[row * 128 + hg * 64 + hw * 16 + r] = acc[q];
        if (r == 0) ps[(hg * 4 + hw) * 16 + row] = accS[q];
    }
}

__global__ __launch_bounds__(256)
void combine_kernel(const float* __restrict__ pacc, const float* __restrict__ psum,
                    const float* __restrict__ WoT, const float* __restrict__ bo,
                    float* __restrict__ out)
{
    const int tid = threadIdx.x;
    const int bid = (blockIdx.x & 7) * 64 + (blockIdx.x >> 3);
    const int b = bid >> 7;
    const int tile = bid & 127;
    const int ibase = tile << 4;

    __shared__ float hl[16][128];
    const size_t pb0 = (size_t)((b * 128 + tile) * 2);
    const float* pa0 = pacc + pb0 * 2048;
    const float* pa1 = pa0 + 2048;
    const float* ps0 = psum + pb0 * 128;
    const float* ps1 = ps0 + 128;

    #pragma unroll
    for (int k = 0; k < 8; ++k) {
        const int idx = k * 256 + tid;        // 0..2047
        const int row = idx >> 7, f = idx & 127, h = f >> 4;
        const float num = pa0[idx] + pa1[idx];
        const float den = ps0[h * 16 + row] + ps1[h * 16 + row];
        const float inv = (den > 0.f) ? 1.f / den : 0.f;   // empty row -> 0
        hl[row][f] = num * inv;
    }
    __syncthreads();

    const int f = tid & 127;
    const int rg = tid >> 7;
    float o[8] = {0.f, 0.f, 0.f, 0.f, 0.f, 0.f, 0.f, 0.f};
    for (int k = 0; k < 128; k += 4) {
        const float w0 = WoT[(k + 0) * 128 + f];
        const float w1 = WoT[(k + 1) * 128 + f];
        const float w2 = WoT[(k + 2) * 128 + f];
        const float w3 = WoT[(k + 3) * 128 + f];
        #pragma unroll
        for (int q = 0; q < 8; ++q) {
            const float4 hv = *reinterpret_cast<const float4*>(&hl[rg * 8 + q][k]);
            o[q] += hv.x * w0 + hv.y * w1 + hv.z * w2 + hv.w * w3;
        }
    }
    const float bv = bo[f];
    #pragma unroll
    for (int q = 0; q < 8; ++q) {
        float v = o[q] + bv;
        v = (v > 0.f) ? v : (__expf(v) - 1.f);
        out[(size_t)(b * 2048 + ibase + rg * 8 + q) * 128 + f] = v;
    }
}

extern "C" void kernel_launch(void* const* d_in, const int* in_sizes, int n_in,
                              void* d_out, int out_size, void* d_ws, size_t ws_size,
                              hipStream_t stream) {
    const float* x   = (const float*)d_in[0];
    const int*   adj = (const int*)d_in[1];
    const float* W   = (const float*)d_in[2];
    const float* a   = (const float*)d_in[3];
    const float* Wo  = (const float*)d_in[4];
    const float* bo  = (const float*)d_in[5];
    float* out = (float*)d_out;

    // ws: vfrag 2MB | EI 512K | EjT 256K | Ej5T 256K | WoT 64K | tmask 2MB |
    //     pacc 8MB | psum 512K   (~13.6 MB)
    char* ws = (char*)d_ws;
    unsigned short* vfrag = (unsigned short*)ws;
    float2* EI  = (float2*)(ws + (size_t)2 * 1024 * 1024);
    float* EjT  = (float*)(EI + 4 * 8 * 2048);
    float* Ej5T = EjT + 4 * 8 * 2048;
    float* WoT  = Ej5T + 4 * 8 * 2048;
    u64* tmask = (u64*)(WoT + 128 * 128);
    float* pacc = (float*)(tmask + (size_t)512 * 512);
    float* psum = pacc + (size_t)1024 * 2048;

    prep_kernel<<<dim3(2048 + 1025), dim3(256), 0, stream>>>(
        x, W, a, Wo, adj, vfrag, EI, EjT, Ej5T, WoT, tmask);
    gat_part<<<dim3(2048), dim3(256), 0, stream>>>(
        tmask, vfrag, EI, EjT, Ej5T, pacc, psum);
    combine_kernel<<<dim3(512), dim3(256), 0, stream>>>(
        pacc, psum, WoT, bo, out);
}